// Round 4
// baseline (2415.189 us; speedup 1.0000x reference)
//
#include <hip/hip_runtime.h>
#include <hip/hip_bf16.h>

#define NN 100000
#define NE 3200000
#define IND 128
#define ED 16
#define HD 64
#define NL 3
#define NG 256
#define BN_EPS 1e-5f

#define EDGE_BLOCKS 4096
#define FUSE_BLOCKS 2048
#define APPLY_BLOCKS 2048

// ================= node projection: h = x @ np_w + np_b =================
__global__ __launch_bounds__(256) void k_node_proj(
    const float* __restrict__ x, const float* __restrict__ w,
    const float* __restrict__ b, float* __restrict__ h)
{
    __shared__ float xs[4][IND];
    const int wave = threadIdx.x >> 6, lane = threadIdx.x & 63;
    const int node = blockIdx.x * 4 + wave;   // grid = NN/4 exactly
    const float2 v = *(const float2*)(x + (size_t)node * IND + lane * 2);
    ((float2*)xs[wave])[lane] = v;
    // same-wave LDS write->read: hardware-ordered per wave
    float acc = b[lane];
#pragma unroll
    for (int k = 0; k < IND; ++k)
        acc = fmaf(xs[wave][k], w[k * HD + lane], acc);
    h[node * HD + lane] = acc;
}

// ================= CSR preprocessing =================
__global__ __launch_bounds__(256) void k_hist(const int* __restrict__ ei,
                                              int* __restrict__ deg)
{
    const int e = blockIdx.x * 256 + threadIdx.x;   // grid = NE/256 exactly
    atomicAdd(&deg[ei[NE + e]], 1);
}

#define SCAN_T 1024
#define SCAN_C 98   // ceil(NN / SCAN_T)
__global__ __launch_bounds__(SCAN_T) void k_scan(const int* __restrict__ deg,
                                                 int* __restrict__ rowptr,
                                                 int* __restrict__ cur)
{
    __shared__ int ps[SCAN_T];
    const int t = threadIdx.x;
    const int begin = t * SCAN_C;
    const int end = min(begin + SCAN_C, NN);
    int s = 0;
    for (int i = begin; i < end; ++i) s += deg[i];
    ps[t] = s;
    __syncthreads();
    for (int off = 1; off < SCAN_T; off <<= 1) {
        int v = (t >= off) ? ps[t - off] : 0;
        __syncthreads();
        ps[t] += v;
        __syncthreads();
    }
    int run = (t == 0) ? 0 : ps[t - 1];
    for (int i = begin; i < end; ++i) {
        rowptr[i] = run;
        cur[i] = run;
        run += deg[i];
    }
    if (t == SCAN_T - 1) rowptr[NN] = run;   // == NE
}

// scatter edges into dst-sorted order.
// MODE 0: copy edge_attr row; MODE 1: store edge id only.
template <int MODE>
__global__ __launch_bounds__(256) void k_scatter(
    const int* __restrict__ ei, const float* __restrict__ ea,
    int* __restrict__ cur, int* __restrict__ perm_src,
    float* __restrict__ ea_perm, int* __restrict__ perm_eid)
{
    const int e = blockIdx.x * 256 + threadIdx.x;   // grid = NE/256 exactly
    const int dst = ei[NE + e];
    const int src = ei[e];
    const int pos = atomicAdd(&cur[dst], 1);
    perm_src[pos] = src;
    if constexpr (MODE == 0) {
        const float4* s4 = (const float4*)(ea + (size_t)e * ED);
        float4* d4 = (float4*)(ea_perm + (size_t)pos * ED);
        d4[0] = s4[0]; d4[1] = s4[1]; d4[2] = s4[2]; d4[3] = s4[3];
    } else {
        perm_eid[pos] = e;
    }
}

// ============ fused: gather-aggregate + GINE MLP + BN partials ============
// wave per node (grid-stride, lane = column). Edge loop unrolled x4 so 4
// random h-gathers are in flight. After aggregation the wave holds the full
// z row -> stage in LDS (same-wave exchange) -> two 64x64 matmuls -> t2 +
// BN sum/sumsq partials. No atomics.
template <int MODE>
__global__ __launch_bounds__(256) void k_fused(
    const float* __restrict__ eadata, const int* __restrict__ perm_src,
    const int* __restrict__ perm_eid, const int* __restrict__ rowptr,
    const float* __restrict__ epw, const float* __restrict__ epb,
    const float* __restrict__ h,
    const float* __restrict__ w1, const float* __restrict__ b1,
    const float* __restrict__ w2, const float* __restrict__ b2,
    float* __restrict__ t2, float* __restrict__ part)
{
    __shared__ float z0s[4][HD];
    __shared__ float t1s[4][HD];
    __shared__ float red[4][2][HD];
    const int lane = threadIdx.x & 63;
    const int wave = threadIdx.x >> 6;
    float wr[ED];
#pragma unroll
    for (int k = 0; k < ED; ++k) wr[k] = epw[k * HD + lane];
    const float bc = epb[lane];
    const float vb1 = b1[lane], vb2 = b2[lane];

    const int wid = __builtin_amdgcn_readfirstlane((blockIdx.x << 2) + wave);
    float s1 = 0.f, s2 = 0.f;

    for (int node = wid; node < NN; node += FUSE_BLOCKS * 4) {
        const int rs = rowptr[node];
        const int re = rowptr[node + 1];
        float acc = 0.f;
        int j = rs;
        for (; j + 4 <= re; j += 4) {
            const int s0 = perm_src[j];
            const int sA = perm_src[j + 1];
            const int sB = perm_src[j + 2];
            const int sC = perm_src[j + 3];
            const float h0 = h[(size_t)s0 * HD + lane];
            const float h1 = h[(size_t)sA * HD + lane];
            const float h2 = h[(size_t)sB * HD + lane];
            const float h3 = h[(size_t)sC * HD + lane];
            int i0 = j, i1 = j + 1, i2 = j + 2, i3 = j + 3;
            if constexpr (MODE == 1) {
                i0 = perm_eid[j]; i1 = perm_eid[j + 1];
                i2 = perm_eid[j + 2]; i3 = perm_eid[j + 3];
            }
            const float* r0 = eadata + (size_t)i0 * ED;
            const float* r1 = eadata + (size_t)i1 * ED;
            const float* r2 = eadata + (size_t)i2 * ED;
            const float* r3 = eadata + (size_t)i3 * ED;
            float e0 = bc, e1 = bc, e2 = bc, e3 = bc;
#pragma unroll
            for (int k = 0; k < ED; ++k) {
                e0 = fmaf(r0[k], wr[k], e0);
                e1 = fmaf(r1[k], wr[k], e1);
                e2 = fmaf(r2[k], wr[k], e2);
                e3 = fmaf(r3[k], wr[k], e3);
            }
            acc += fmaxf(h0 + e0, 0.f) + fmaxf(h1 + e1, 0.f)
                 + fmaxf(h2 + e2, 0.f) + fmaxf(h3 + e3, 0.f);
        }
        for (; j < re; ++j) {
            const int s0 = perm_src[j];
            const int i0 = (MODE == 1) ? perm_eid[j] : j;
            const float* r0 = eadata + (size_t)i0 * ED;
            float e0 = bc;
#pragma unroll
            for (int k = 0; k < ED; ++k) e0 = fmaf(r0[k], wr[k], e0);
            acc += fmaxf(h[(size_t)s0 * HD + lane] + e0, 0.f);
        }
        const int idx = node * HD + lane;
        // z row lives in this wave: stage and run the MLP in place.
        z0s[wave][lane] = acc + h[idx];
        float a = vb1;
#pragma unroll
        for (int k = 0; k < HD; ++k)
            a = fmaf(z0s[wave][k], w1[k * HD + lane], a);
        a = fmaxf(a, 0.f);
        t1s[wave][lane] = a;
        float o = vb2;
#pragma unroll
        for (int k = 0; k < HD; ++k)
            o = fmaf(t1s[wave][k], w2[k * HD + lane], o);
        t2[idx] = o;
        s1 += o;
        s2 += o * o;
    }
    red[wave][0][lane] = s1;
    red[wave][1][lane] = s2;
    __syncthreads();
    if (wave == 0) {
        float a = red[0][0][lane] + red[1][0][lane] + red[2][0][lane] + red[3][0][lane];
        float c = red[0][1][lane] + red[1][1][lane] + red[2][1][lane] + red[3][1][lane];
        part[blockIdx.x * 128 + lane] = a;
        part[blockIdx.x * 128 + 64 + lane] = c;
    }
}

// ================= fallback: atomic edge scatter (mode 2) =================
__global__ __launch_bounds__(256) void k_edge_msg(
    const float* __restrict__ ea, const int* __restrict__ ei,
    const float* __restrict__ epw, const float* __restrict__ epb,
    const float* __restrict__ h, float* __restrict__ agg)
{
    const int lane = threadIdx.x & 63;
    float wr[ED];
#pragma unroll
    for (int k = 0; k < ED; ++k) wr[k] = epw[k * HD + lane];
    const float bc = epb[lane];

    int wid = (blockIdx.x << 2) + (threadIdx.x >> 6);
    wid = __builtin_amdgcn_readfirstlane(wid);
    const int nw = EDGE_BLOCKS * 4;
    for (int e = wid; e < NE; e += nw) {
        const int src = ei[e];
        const int dst = ei[NE + e];
        float acc = bc;
#pragma unroll
        for (int k = 0; k < ED; ++k)
            acc = fmaf(ea[e * ED + k], wr[k], acc);
        float m = fmaxf(h[src * HD + lane] + acc, 0.f);
        atomicAdd(&agg[dst * HD + lane], m);
    }
}

// ================= standalone MLP (mode-2 fallback only) =================
__global__ __launch_bounds__(256) void k_mlp(
    const float* __restrict__ h, float* zin_t2,
    const float* __restrict__ w1, const float* __restrict__ b1,
    const float* __restrict__ w2, const float* __restrict__ b2,
    float* __restrict__ part)
{
    __shared__ float z0s[4][HD];
    __shared__ float t1s[4][HD];
    __shared__ float red[4][2][HD];
    const int wave = threadIdx.x >> 6, lane = threadIdx.x & 63;
    const float vb1 = b1[lane], vb2 = b2[lane];
    float s1 = 0.f, s2 = 0.f;
    for (int node = blockIdx.x * 4 + wave; node < NN; node += FUSE_BLOCKS * 4) {
        const int idx = node * HD + lane;
        z0s[wave][lane] = h[idx] + zin_t2[idx];
        float a = vb1;
#pragma unroll
        for (int k = 0; k < HD; ++k)
            a = fmaf(z0s[wave][k], w1[k * HD + lane], a);
        a = fmaxf(a, 0.f);
        t1s[wave][lane] = a;
        float o = vb2;
#pragma unroll
        for (int k = 0; k < HD; ++k)
            o = fmaf(t1s[wave][k], w2[k * HD + lane], o);
        zin_t2[idx] = o;
        s1 += o;
        s2 += o * o;
    }
    red[wave][0][lane] = s1;
    red[wave][1][lane] = s2;
    __syncthreads();
    if (wave == 0) {
        float a = red[0][0][lane] + red[1][0][lane] + red[2][0][lane] + red[3][0][lane];
        float c = red[0][1][lane] + red[1][1][lane] + red[2][1][lane] + red[3][1][lane];
        part[blockIdx.x * 128 + lane] = a;
        part[blockIdx.x * 128 + 64 + lane] = c;
    }
}

// ================= BN stats finalize (1 block x 1024) =================
__global__ __launch_bounds__(1024) void k_bn_final(
    const float* __restrict__ part,
    const float* __restrict__ g, const float* __restrict__ b,
    float* __restrict__ bnp)
{
    __shared__ float red[16][2][HD];
    const int c = threadIdx.x & 63;
    const int s = threadIdx.x >> 6;
    float s1 = 0.f, s2 = 0.f;
    for (int i = s; i < FUSE_BLOCKS; i += 16) {
        s1 += part[i * 128 + c];
        s2 += part[i * 128 + 64 + c];
    }
    red[s][0][c] = s1;
    red[s][1][c] = s2;
    __syncthreads();
    if (s == 0) {
        float a = 0.f, q = 0.f;
#pragma unroll
        for (int i = 0; i < 16; ++i) { a += red[i][0][c]; q += red[i][1][c]; }
        const float mu  = a / (float)NN;
        const float var = q / (float)NN - mu * mu;
        const float rstd = rsqrtf(var + BN_EPS);
        const float sc = rstd * g[c];
        bnp[c] = sc;
        bnp[64 + c] = b[c] - mu * sc;
    }
}

// ================= BN apply + ReLU (h lives in d_out, f32) =================
__global__ __launch_bounds__(256) void k_bn_apply(
    const float* __restrict__ t2, const float* __restrict__ bnp,
    float* __restrict__ h)
{
    const int lane = threadIdx.x & 63;
    const float sc = bnp[lane];
    const float sh = bnp[64 + lane];
    int i = blockIdx.x * 256 + threadIdx.x;
    const int stride = APPLY_BLOCKS * 256;
    for (; i < NN * HD; i += stride)
        h[i] = fmaxf(t2[i] * sc + sh, 0.f);
}

// ================= global mean pool (batch sorted; 4 waves/graph) ==========
__global__ __launch_bounds__(256) void k_pool(
    const float* __restrict__ h, const int* __restrict__ batch,
    float* __restrict__ emb)
{
    __shared__ float red[4][HD];
    const int g = blockIdx.x;
    const int lane = threadIdx.x & 63;
    const int wave = threadIdx.x >> 6;
    int lo = 0, hi = NN;
    while (lo < hi) { int m = (lo + hi) >> 1; if (batch[m] < g) lo = m + 1; else hi = m; }
    const int start = lo;
    hi = NN;
    while (lo < hi) { int m = (lo + hi) >> 1; if (batch[m] <= g) lo = m + 1; else hi = m; }
    const int end = lo;
    float acc = 0.f;
    for (int n = start + wave; n < end; n += 4) acc += h[(size_t)n * HD + lane];
    red[wave][lane] = acc;
    __syncthreads();
    if (wave == 0) {
        float a = red[0][lane] + red[1][lane] + red[2][lane] + red[3][lane];
        emb[g * HD + lane] = a / fmaxf((float)(end - start), 1.f);
    }
}

extern "C" void kernel_launch(void* const* d_in, const int* in_sizes, int n_in,
                              void* d_out, int out_size, void* d_ws, size_t ws_size,
                              hipStream_t stream)
{
    const float* x     = (const float*)d_in[0];
    const float* ea    = (const float*)d_in[1];
    const int*   ei    = (const int*)d_in[2];
    const int*   batch = (const int*)d_in[3];
    const float* np_w  = (const float*)d_in[4];
    const float* np_b  = (const float*)d_in[5];
    const float* ep_w  = (const float*)d_in[6];
    const float* ep_b  = (const float*)d_in[7];
    const float* w1    = (const float*)d_in[8];
    const float* b1    = (const float*)d_in[9];
    const float* w2    = (const float*)d_in[10];
    const float* b2    = (const float*)d_in[11];
    const float* bng   = (const float*)d_in[12];
    const float* bnb   = (const float*)d_in[13];

    // h lives directly in d_out (f32): [NN*HD] then graph_emb [NG*HD]
    float* h   = (float*)d_out;
    float* emb = h + (size_t)NN * HD;

    char* ws = (char*)d_ws;
    float* agg      = (float*)(ws);                 // 25,600,000 (t2 / z)
    float* part     = (float*)(ws + 25600000);      //  1,048,576
    float* bnp      = (float*)(ws + 26648576);      //        512
    int*   deg      = (int*)  (ws + 26649088);      //    400,000
    int*   rowptr   = (int*)  (ws + 27049088);      //    400,016
    int*   cur      = (int*)  (ws + 27449104);      //    400,000
    int*   perm_src = (int*)  (ws + 27849104);      // 12,800,000
    float* ea_perm  = (float*)(ws + 40649104);      // 204,800,000 (mode 0)
    int*   perm_eid = (int*)  (ws + 40649104);      //  12,800,000 (mode 1)

    const size_t NEED_A = 40649104u + 204800000u;   // ~245.4 MB
    const size_t NEED_B = 40649104u + 12800000u;    // ~53.4 MB
    const int mode = (ws_size >= NEED_A) ? 0 : (ws_size >= NEED_B) ? 1 : 2;

    k_node_proj<<<NN / 4, 256, 0, stream>>>(x, np_w, np_b, h);

    if (mode != 2) {
        hipMemsetAsync(deg, 0, NN * sizeof(int), stream);
        k_hist<<<NE / 256, 256, 0, stream>>>(ei, deg);
        k_scan<<<1, SCAN_T, 0, stream>>>(deg, rowptr, cur);
        if (mode == 0)
            k_scatter<0><<<NE / 256, 256, 0, stream>>>(ei, ea, cur, perm_src, ea_perm, perm_eid);
        else
            k_scatter<1><<<NE / 256, 256, 0, stream>>>(ei, ea, cur, perm_src, ea_perm, perm_eid);
    }

    for (int l = 0; l < NL; ++l) {
        if (mode == 0) {
            k_fused<0><<<FUSE_BLOCKS, 256, 0, stream>>>(
                ea_perm, perm_src, perm_eid, rowptr, ep_w, ep_b, h,
                w1 + l * HD * HD, b1 + l * HD, w2 + l * HD * HD, b2 + l * HD,
                agg, part);
        } else if (mode == 1) {
            k_fused<1><<<FUSE_BLOCKS, 256, 0, stream>>>(
                ea, perm_src, perm_eid, rowptr, ep_w, ep_b, h,
                w1 + l * HD * HD, b1 + l * HD, w2 + l * HD * HD, b2 + l * HD,
                agg, part);
        } else {
            hipMemsetAsync(agg, 0, (size_t)NN * HD * sizeof(float), stream);
            k_edge_msg<<<EDGE_BLOCKS, 256, 0, stream>>>(ea, ei, ep_w, ep_b, h, agg);
            k_mlp<<<FUSE_BLOCKS, 256, 0, stream>>>(h, agg, w1 + l * HD * HD, b1 + l * HD,
                                                   w2 + l * HD * HD, b2 + l * HD, part);
        }
        k_bn_final<<<1, 1024, 0, stream>>>(part, bng + l * HD, bnb + l * HD, bnp);
        k_bn_apply<<<APPLY_BLOCKS, 256, 0, stream>>>(agg, bnp, h);
    }

    k_pool<<<NG, 256, 0, stream>>>(h, batch, emb);
}

// Round 5
// 1861.448 us; speedup vs baseline: 1.2975x; 1.2975x over previous
//
#include <hip/hip_runtime.h>
#include <hip/hip_bf16.h>

#define NN 100000
#define NE 3200000
#define IND 128
#define ED 16
#define HD 64
#define NL 3
#define NG 256
#define BN_EPS 1e-5f

#define EDGE_BLOCKS 4096
#define MLP_BLOCKS 2048
#define APPLY_BLOCKS 2048

// ================= node projection: h = x @ np_w + np_b =================
__global__ __launch_bounds__(256) void k_node_proj(
    const float* __restrict__ x, const float* __restrict__ w,
    const float* __restrict__ b, float* __restrict__ h)
{
    __shared__ float xs[4][IND];
    const int wave = threadIdx.x >> 6, lane = threadIdx.x & 63;
    const int node = blockIdx.x * 4 + wave;   // grid = NN/4 exactly
    const float2 v = *(const float2*)(x + (size_t)node * IND + lane * 2);
    ((float2*)xs[wave])[lane] = v;
    // same-wave LDS write->read: hardware-ordered per wave
    float acc = b[lane];
#pragma unroll
    for (int k = 0; k < IND; ++k)
        acc = fmaf(xs[wave][k], w[k * HD + lane], acc);
    h[node * HD + lane] = acc;
}

// ================= CSR preprocessing =================
__global__ __launch_bounds__(256) void k_hist(const int* __restrict__ ei,
                                              int* __restrict__ deg)
{
    const int e = blockIdx.x * 256 + threadIdx.x;   // grid = NE/256 exactly
    atomicAdd(&deg[ei[NE + e]], 1);
}

#define SCAN_T 1024
#define SCAN_C 98   // ceil(NN / SCAN_T)
__global__ __launch_bounds__(SCAN_T) void k_scan(const int* __restrict__ deg,
                                                 int* __restrict__ rowptr,
                                                 int* __restrict__ cur)
{
    __shared__ int ps[SCAN_T];
    const int t = threadIdx.x;
    const int begin = t * SCAN_C;
    const int end = min(begin + SCAN_C, NN);
    int s = 0;
    for (int i = begin; i < end; ++i) s += deg[i];
    ps[t] = s;
    __syncthreads();
    for (int off = 1; off < SCAN_T; off <<= 1) {
        int v = (t >= off) ? ps[t - off] : 0;
        __syncthreads();
        ps[t] += v;
        __syncthreads();
    }
    int run = (t == 0) ? 0 : ps[t - 1];
    for (int i = begin; i < end; ++i) {
        rowptr[i] = run;
        cur[i] = run;
        run += deg[i];
    }
    if (t == SCAN_T - 1) rowptr[NN] = run;   // == NE
}

// scatter edge ids into dst-sorted order (random 4B writes only)
__global__ __launch_bounds__(256) void k_scatter(
    const int* __restrict__ ei, int* __restrict__ cur,
    int* __restrict__ perm_src, int* __restrict__ perm_eid)
{
    const int e = blockIdx.x * 256 + threadIdx.x;   // grid = NE/256 exactly
    const int dst = ei[NE + e];
    const int src = ei[e];
    const int pos = atomicAdd(&cur[dst], 1);
    perm_src[pos] = src;
    perm_eid[pos] = e;
}

// gather-permute edge_attr rows: random 64B reads, fully coalesced writes
__global__ __launch_bounds__(256) void k_permute(
    const float* __restrict__ ea, const int* __restrict__ perm_eid,
    float* __restrict__ ea_perm)
{
    const int pos = blockIdx.x * 256 + threadIdx.x;  // grid = NE*4/256
    const int eid = perm_eid[pos >> 2];
    const int q = pos & 3;
    const float4 v = ((const float4*)(ea + (size_t)eid * ED))[q];
    ((float4*)ea_perm)[pos] = v;
}

// ================= gather aggregation (x8 unrolled, lean VGPR) ============
// wave per node (lane = column). Edge-side loads wave-uniform -> scalar;
// 8 random h-gathers issued back-to-back before any consumption.
// Writes z = h[node] + sum_j relu(h[src_j] + eproj_j). No atomics.
template <int MODE>
__global__ __launch_bounds__(256) void k_gather(
    const float* __restrict__ eadata, const int* __restrict__ perm_src,
    const int* __restrict__ perm_eid, const int* __restrict__ rowptr,
    const float* __restrict__ epw, const float* __restrict__ epb,
    const float* __restrict__ h, float* __restrict__ z)
{
    const int lane = threadIdx.x & 63;
    float wr[ED];
#pragma unroll
    for (int k = 0; k < ED; ++k) wr[k] = epw[k * HD + lane];
    const float bc = epb[lane];

    const int node = __builtin_amdgcn_readfirstlane((blockIdx.x << 2) + (threadIdx.x >> 6));
    const int rs = rowptr[node];
    const int re = rowptr[node + 1];

    float acc = 0.f;
    int j = rs;
    for (; j + 8 <= re; j += 8) {
        int s[8];
#pragma unroll
        for (int m = 0; m < 8; ++m) s[m] = perm_src[j + m];
        float hv[8];
#pragma unroll
        for (int m = 0; m < 8; ++m) hv[m] = h[(size_t)s[m] * HD + lane];
        float ev[8];
#pragma unroll
        for (int m = 0; m < 8; ++m) {
            const int idx = (MODE == 1) ? perm_eid[j + m] : (j + m);
            const float* r = eadata + (size_t)idx * ED;
            float e = bc;
#pragma unroll
            for (int k = 0; k < ED; ++k) e = fmaf(r[k], wr[k], e);
            ev[m] = e;
        }
#pragma unroll
        for (int m = 0; m < 8; ++m) acc += fmaxf(hv[m] + ev[m], 0.f);
    }
    for (; j < re; ++j) {
        const int s0 = perm_src[j];
        const int i0 = (MODE == 1) ? perm_eid[j] : j;
        const float* r0 = eadata + (size_t)i0 * ED;
        float e0 = bc;
#pragma unroll
        for (int k = 0; k < ED; ++k) e0 = fmaf(r0[k], wr[k], e0);
        acc += fmaxf(h[(size_t)s0 * HD + lane] + e0, 0.f);
    }
    const int idx = node * HD + lane;
    z[idx] = acc + h[idx];
}

// ================= fallback: atomic edge scatter (mode 2) =================
__global__ __launch_bounds__(256) void k_edge_msg(
    const float* __restrict__ ea, const int* __restrict__ ei,
    const float* __restrict__ epw, const float* __restrict__ epb,
    const float* __restrict__ h, float* __restrict__ agg)
{
    const int lane = threadIdx.x & 63;
    float wr[ED];
#pragma unroll
    for (int k = 0; k < ED; ++k) wr[k] = epw[k * HD + lane];
    const float bc = epb[lane];

    int wid = (blockIdx.x << 2) + (threadIdx.x >> 6);
    wid = __builtin_amdgcn_readfirstlane(wid);
    const int nw = EDGE_BLOCKS * 4;
    for (int e = wid; e < NE; e += nw) {
        const int src = ei[e];
        const int dst = ei[NE + e];
        float acc = bc;
#pragma unroll
        for (int k = 0; k < ED; ++k)
            acc = fmaf(ea[e * ED + k], wr[k], acc);
        float m = fmaxf(h[src * HD + lane] + acc, 0.f);
        atomicAdd(&agg[dst * HD + lane], m);
    }
}

// ================= per-layer MLP + BN partial stats =================
// ADD_H: z0 = h + zin (atomic path) vs z0 = zin (CSR path, h already added)
template <bool ADD_H>
__global__ __launch_bounds__(256) void k_mlp(
    const float* __restrict__ h, float* zin_t2,
    const float* __restrict__ w1, const float* __restrict__ b1,
    const float* __restrict__ w2, const float* __restrict__ b2,
    float* __restrict__ part)
{
    __shared__ float z0s[4][HD];
    __shared__ float t1s[4][HD];
    __shared__ float red[4][2][HD];
    const int wave = threadIdx.x >> 6, lane = threadIdx.x & 63;
    const float vb1 = b1[lane], vb2 = b2[lane];
    float s1 = 0.f, s2 = 0.f;
    for (int node = blockIdx.x * 4 + wave; node < NN; node += MLP_BLOCKS * 4) {
        const int idx = node * HD + lane;
        z0s[wave][lane] = ADD_H ? (h[idx] + zin_t2[idx]) : zin_t2[idx];
        float a = vb1;
#pragma unroll
        for (int k = 0; k < HD; ++k)
            a = fmaf(z0s[wave][k], w1[k * HD + lane], a);
        a = fmaxf(a, 0.f);
        t1s[wave][lane] = a;
        float o = vb2;
#pragma unroll
        for (int k = 0; k < HD; ++k)
            o = fmaf(t1s[wave][k], w2[k * HD + lane], o);
        zin_t2[idx] = o;
        s1 += o;
        s2 += o * o;
    }
    red[wave][0][lane] = s1;
    red[wave][1][lane] = s2;
    __syncthreads();
    if (wave == 0) {
        float a = red[0][0][lane] + red[1][0][lane] + red[2][0][lane] + red[3][0][lane];
        float c = red[0][1][lane] + red[1][1][lane] + red[2][1][lane] + red[3][1][lane];
        part[blockIdx.x * 128 + lane] = a;
        part[blockIdx.x * 128 + 64 + lane] = c;
    }
}

// ================= BN stats finalize (1 block x 1024) =================
__global__ __launch_bounds__(1024) void k_bn_final(
    const float* __restrict__ part,
    const float* __restrict__ g, const float* __restrict__ b,
    float* __restrict__ bnp)
{
    __shared__ float red[16][2][HD];
    const int c = threadIdx.x & 63;
    const int s = threadIdx.x >> 6;
    float s1 = 0.f, s2 = 0.f;
    for (int i = s; i < MLP_BLOCKS; i += 16) {
        s1 += part[i * 128 + c];
        s2 += part[i * 128 + 64 + c];
    }
    red[s][0][c] = s1;
    red[s][1][c] = s2;
    __syncthreads();
    if (s == 0) {
        float a = 0.f, q = 0.f;
#pragma unroll
        for (int i = 0; i < 16; ++i) { a += red[i][0][c]; q += red[i][1][c]; }
        const float mu  = a / (float)NN;
        const float var = q / (float)NN - mu * mu;
        const float rstd = rsqrtf(var + BN_EPS);
        const float sc = rstd * g[c];
        bnp[c] = sc;
        bnp[64 + c] = b[c] - mu * sc;
    }
}

// ================= BN apply + ReLU (h lives in d_out, f32) =================
__global__ __launch_bounds__(256) void k_bn_apply(
    const float* __restrict__ t2, const float* __restrict__ bnp,
    float* __restrict__ h)
{
    const int lane = threadIdx.x & 63;
    const float sc = bnp[lane];
    const float sh = bnp[64 + lane];
    int i = blockIdx.x * 256 + threadIdx.x;
    const int stride = APPLY_BLOCKS * 256;
    for (; i < NN * HD; i += stride)
        h[i] = fmaxf(t2[i] * sc + sh, 0.f);
}

// ================= global mean pool (batch sorted; 4 waves/graph) ==========
__global__ __launch_bounds__(256) void k_pool(
    const float* __restrict__ h, const int* __restrict__ batch,
    float* __restrict__ emb)
{
    __shared__ float red[4][HD];
    const int g = blockIdx.x;
    const int lane = threadIdx.x & 63;
    const int wave = threadIdx.x >> 6;
    int lo = 0, hi = NN;
    while (lo < hi) { int m = (lo + hi) >> 1; if (batch[m] < g) lo = m + 1; else hi = m; }
    const int start = lo;
    hi = NN;
    while (lo < hi) { int m = (lo + hi) >> 1; if (batch[m] <= g) lo = m + 1; else hi = m; }
    const int end = lo;
    float acc = 0.f;
    for (int n = start + wave; n < end; n += 4) acc += h[(size_t)n * HD + lane];
    red[wave][lane] = acc;
    __syncthreads();
    if (wave == 0) {
        float a = red[0][lane] + red[1][lane] + red[2][lane] + red[3][lane];
        emb[g * HD + lane] = a / fmaxf((float)(end - start), 1.f);
    }
}

extern "C" void kernel_launch(void* const* d_in, const int* in_sizes, int n_in,
                              void* d_out, int out_size, void* d_ws, size_t ws_size,
                              hipStream_t stream)
{
    const float* x     = (const float*)d_in[0];
    const float* ea    = (const float*)d_in[1];
    const int*   ei    = (const int*)d_in[2];
    const int*   batch = (const int*)d_in[3];
    const float* np_w  = (const float*)d_in[4];
    const float* np_b  = (const float*)d_in[5];
    const float* ep_w  = (const float*)d_in[6];
    const float* ep_b  = (const float*)d_in[7];
    const float* w1    = (const float*)d_in[8];
    const float* b1    = (const float*)d_in[9];
    const float* w2    = (const float*)d_in[10];
    const float* b2    = (const float*)d_in[11];
    const float* bng   = (const float*)d_in[12];
    const float* bnb   = (const float*)d_in[13];

    // h lives directly in d_out (f32): [NN*HD] then graph_emb [NG*HD]
    float* h   = (float*)d_out;
    float* emb = h + (size_t)NN * HD;

    char* ws = (char*)d_ws;
    float* agg      = (float*)(ws);                 // 25,600,000 (z / t2)
    float* part     = (float*)(ws + 25600000);      //  1,048,576
    float* bnp      = (float*)(ws + 26648576);      //        512
    int*   deg      = (int*)  (ws + 26649088);      //    400,000
    int*   rowptr   = (int*)  (ws + 27049088);      //    400,016
    int*   cur      = (int*)  (ws + 27449104);      //    400,000
    int*   perm_src = (int*)  (ws + 27849104);      // 12,800,000
    float* ea_perm  = (float*)(ws + 40649104);      // 204,800,000 (mode 0)
    int*   perm_eid = (int*)  (ws + 40649104);      //  12,800,000 (mode 1)

    const size_t NEED_A = 40649104u + 204800000u;   // ~245.4 MB
    const size_t NEED_B = 40649104u + 12800000u;    // ~53.4 MB
    const int mode = (ws_size >= NEED_A) ? 0 : (ws_size >= NEED_B) ? 1 : 2;

    // mode 0: perm_eid is only needed during preprocessing -> park it in agg
    // (agg's first real use, as z, happens after k_permute consumed it).
    int* eid_tmp = (mode == 0) ? (int*)agg : perm_eid;

    k_node_proj<<<NN / 4, 256, 0, stream>>>(x, np_w, np_b, h);

    if (mode != 2) {
        hipMemsetAsync(deg, 0, NN * sizeof(int), stream);
        k_hist<<<NE / 256, 256, 0, stream>>>(ei, deg);
        k_scan<<<1, SCAN_T, 0, stream>>>(deg, rowptr, cur);
        k_scatter<<<NE / 256, 256, 0, stream>>>(ei, cur, perm_src, eid_tmp);
        if (mode == 0)
            k_permute<<<NE * 4 / 256, 256, 0, stream>>>(ea, eid_tmp, ea_perm);
    }

    for (int l = 0; l < NL; ++l) {
        if (mode == 0) {
            k_gather<0><<<NN / 4, 256, 0, stream>>>(ea_perm, perm_src, perm_eid,
                                                    rowptr, ep_w, ep_b, h, agg);
            k_mlp<false><<<MLP_BLOCKS, 256, 0, stream>>>(h, agg, w1 + l * HD * HD, b1 + l * HD,
                                                         w2 + l * HD * HD, b2 + l * HD, part);
        } else if (mode == 1) {
            k_gather<1><<<NN / 4, 256, 0, stream>>>(ea, perm_src, perm_eid,
                                                    rowptr, ep_w, ep_b, h, agg);
            k_mlp<false><<<MLP_BLOCKS, 256, 0, stream>>>(h, agg, w1 + l * HD * HD, b1 + l * HD,
                                                         w2 + l * HD * HD, b2 + l * HD, part);
        } else {
            hipMemsetAsync(agg, 0, (size_t)NN * HD * sizeof(float), stream);
            k_edge_msg<<<EDGE_BLOCKS, 256, 0, stream>>>(ea, ei, ep_w, ep_b, h, agg);
            k_mlp<true><<<MLP_BLOCKS, 256, 0, stream>>>(h, agg, w1 + l * HD * HD, b1 + l * HD,
                                                        w2 + l * HD * HD, b2 + l * HD, part);
        }
        k_bn_final<<<1, 1024, 0, stream>>>(part, bng + l * HD, bnb + l * HD, bnp);
        k_bn_apply<<<APPLY_BLOCKS, 256, 0, stream>>>(agg, bnp, h);
    }

    k_pool<<<NG, 256, 0, stream>>>(h, batch, emb);
}

// Round 6
// 1748.616 us; speedup vs baseline: 1.3812x; 1.0645x over previous
//
#include <hip/hip_runtime.h>
#include <hip/hip_bf16.h>

#define NN 100000
#define NE 3200000
#define IND 128
#define ED 16
#define HD 64
#define NL 3
#define NG 256
#define BN_EPS 1e-5f

#define EDGE_BLOCKS 4096
#define MLP_BLOCKS 2048
#define APPLY_BLOCKS 2048

typedef unsigned int uint32;
typedef unsigned short ushort16;

// f32 -> bf16 bits, round-to-nearest-even
__device__ __forceinline__ ushort16 f2b(float f) {
    uint32 u = __float_as_uint(f);
    u = (u + 0x7fffu + ((u >> 16) & 1u)) >> 16;
    return (ushort16)u;
}
__device__ __forceinline__ float b2f(ushort16 b) {
    return __uint_as_float(((uint32)b) << 16);
}

// ================= node projection: h = x @ np_w + np_b =================
__global__ __launch_bounds__(256) void k_node_proj(
    const float* __restrict__ x, const float* __restrict__ w,
    const float* __restrict__ b, float* __restrict__ h,
    ushort16* __restrict__ hb)
{
    __shared__ float xs[4][IND];
    const int wave = threadIdx.x >> 6, lane = threadIdx.x & 63;
    const int node = blockIdx.x * 4 + wave;   // grid = NN/4 exactly
    const float2 v = *(const float2*)(x + (size_t)node * IND + lane * 2);
    ((float2*)xs[wave])[lane] = v;
    // same-wave LDS write->read: hardware-ordered per wave
    float acc = b[lane];
#pragma unroll
    for (int k = 0; k < IND; ++k)
        acc = fmaf(xs[wave][k], w[k * HD + lane], acc);
    h[node * HD + lane] = acc;
    if (hb) hb[node * HD + lane] = f2b(acc);
}

// ================= CSR preprocessing =================
__global__ __launch_bounds__(256) void k_hist(const int* __restrict__ ei,
                                              int* __restrict__ deg)
{
    const int e = blockIdx.x * 256 + threadIdx.x;   // grid = NE/256 exactly
    atomicAdd(&deg[ei[NE + e]], 1);
}

#define SCAN_T 1024
#define SCAN_C 98   // ceil(NN / SCAN_T)
__global__ __launch_bounds__(SCAN_T) void k_scan(const int* __restrict__ deg,
                                                 int* __restrict__ rowptr,
                                                 int* __restrict__ cur)
{
    __shared__ int ps[SCAN_T];
    const int t = threadIdx.x;
    const int begin = t * SCAN_C;
    const int end = min(begin + SCAN_C, NN);
    int s = 0;
    for (int i = begin; i < end; ++i) s += deg[i];
    ps[t] = s;
    __syncthreads();
    for (int off = 1; off < SCAN_T; off <<= 1) {
        int v = (t >= off) ? ps[t - off] : 0;
        __syncthreads();
        ps[t] += v;
        __syncthreads();
    }
    int run = (t == 0) ? 0 : ps[t - 1];
    for (int i = begin; i < end; ++i) {
        rowptr[i] = run;
        cur[i] = run;
        run += deg[i];
    }
    if (t == SCAN_T - 1) rowptr[NN] = run;   // == NE
}

// scatter packed (src, eid) into dst-sorted order: ONE 8B random write/edge
__global__ __launch_bounds__(256) void k_scatter(
    const int* __restrict__ ei, int* __restrict__ cur,
    int2* __restrict__ perm_se)
{
    const int e = blockIdx.x * 256 + threadIdx.x;   // grid = NE/256 exactly
    const int dst = ei[NE + e];
    const int src = ei[e];
    const int pos = atomicAdd(&cur[dst], 1);
    perm_se[pos] = make_int2(src, e);
}

// permute edge_attr rows to dst-order, converting to bf16.
// 4 threads/edge: random float4 reads, fully coalesced ushort4 writes.
__global__ __launch_bounds__(256) void k_permute(
    const float* __restrict__ ea, const int2* __restrict__ perm_se,
    ushort16* __restrict__ ea_perm)
{
    const int pos = blockIdx.x * 256 + threadIdx.x;  // grid = NE*4/256
    const int p = pos >> 2, q = pos & 3;
    const int eid = perm_se[p].y;
    const float4 v = ((const float4*)(ea + (size_t)eid * ED))[q];
    ushort4 o;
    o.x = f2b(v.x); o.y = f2b(v.y); o.z = f2b(v.z); o.w = f2b(v.w);
    ((ushort4*)ea_perm)[pos] = o;
}

// ================= gather aggregation (bf16 tables, x8 in flight) =========
// wave per node (lane = column). perm_se/ea rows wave-uniform -> scalar
// loads (bf16 unpack = SGPR shift, free); h-gathers are bf16 128B rows.
// Writes z = h[node] + sum_j relu(h_b[src_j] + eproj_j). No atomics.
template <int MODE>
__global__ __launch_bounds__(256) void k_gather(
    const ushort16* __restrict__ eab,      // MODE 0: bf16 permuted ea
    const float* __restrict__ eaf,         // MODE 1: original f32 ea
    const int2* __restrict__ perm_se,
    const int* __restrict__ rowptr,
    const float* __restrict__ epw, const float* __restrict__ epb,
    const ushort16* __restrict__ hb, const float* __restrict__ h,
    float* __restrict__ z)
{
    const int lane = threadIdx.x & 63;
    float wr[ED];
#pragma unroll
    for (int k = 0; k < ED; ++k) wr[k] = epw[k * HD + lane];
    const float bc = epb[lane];

    const int node = __builtin_amdgcn_readfirstlane((blockIdx.x << 2) + (threadIdx.x >> 6));
    const int rs = rowptr[node];
    const int re = rowptr[node + 1];

    float acc = 0.f;
    int j = rs;
    for (; j + 8 <= re; j += 8) {
        int s[8], eid[8];
#pragma unroll
        for (int m = 0; m < 8; ++m) {
            const int2 se = perm_se[j + m];
            s[m] = se.x; eid[m] = se.y;
        }
        float hv[8];
#pragma unroll
        for (int m = 0; m < 8; ++m) hv[m] = b2f(hb[(size_t)s[m] * HD + lane]);
        float ev[8];
#pragma unroll
        for (int m = 0; m < 8; ++m) {
            float e = bc;
            if constexpr (MODE == 0) {
                const uint32* r = (const uint32*)(eab + (size_t)(j + m) * ED);
#pragma unroll
                for (int k2 = 0; k2 < ED / 2; ++k2) {
                    const uint32 u = r[k2];
                    e = fmaf(__uint_as_float(u << 16), wr[2 * k2], e);
                    e = fmaf(__uint_as_float(u & 0xffff0000u), wr[2 * k2 + 1], e);
                }
            } else {
                const float* r = eaf + (size_t)eid[m] * ED;
#pragma unroll
                for (int k = 0; k < ED; ++k) e = fmaf(r[k], wr[k], e);
            }
            ev[m] = e;
        }
#pragma unroll
        for (int m = 0; m < 8; ++m) acc += fmaxf(hv[m] + ev[m], 0.f);
    }
    for (; j < re; ++j) {
        const int2 se = perm_se[j];
        float e = bc;
        if constexpr (MODE == 0) {
            const uint32* r = (const uint32*)(eab + (size_t)j * ED);
#pragma unroll
            for (int k2 = 0; k2 < ED / 2; ++k2) {
                const uint32 u = r[k2];
                e = fmaf(__uint_as_float(u << 16), wr[2 * k2], e);
                e = fmaf(__uint_as_float(u & 0xffff0000u), wr[2 * k2 + 1], e);
            }
        } else {
            const float* r = eaf + (size_t)se.y * ED;
#pragma unroll
            for (int k = 0; k < ED; ++k) e = fmaf(r[k], wr[k], e);
        }
        acc += fmaxf(b2f(hb[(size_t)se.x * HD + lane]) + e, 0.f);
    }
    const int idx = node * HD + lane;
    z[idx] = acc + h[idx];
}

// ================= fallback: atomic edge scatter (mode 2) =================
__global__ __launch_bounds__(256) void k_edge_msg(
    const float* __restrict__ ea, const int* __restrict__ ei,
    const float* __restrict__ epw, const float* __restrict__ epb,
    const float* __restrict__ h, float* __restrict__ agg)
{
    const int lane = threadIdx.x & 63;
    float wr[ED];
#pragma unroll
    for (int k = 0; k < ED; ++k) wr[k] = epw[k * HD + lane];
    const float bc = epb[lane];

    int wid = (blockIdx.x << 2) + (threadIdx.x >> 6);
    wid = __builtin_amdgcn_readfirstlane(wid);
    const int nw = EDGE_BLOCKS * 4;
    for (int e = wid; e < NE; e += nw) {
        const int src = ei[e];
        const int dst = ei[NE + e];
        float acc = bc;
#pragma unroll
        for (int k = 0; k < ED; ++k)
            acc = fmaf(ea[e * ED + k], wr[k], acc);
        float m = fmaxf(h[src * HD + lane] + acc, 0.f);
        atomicAdd(&agg[dst * HD + lane], m);
    }
}

// ================= per-layer MLP + BN partial stats =================
template <bool ADD_H>
__global__ __launch_bounds__(256) void k_mlp(
    const float* __restrict__ h, float* zin_t2,
    const float* __restrict__ w1, const float* __restrict__ b1,
    const float* __restrict__ w2, const float* __restrict__ b2,
    float* __restrict__ part)
{
    __shared__ float z0s[4][HD];
    __shared__ float t1s[4][HD];
    __shared__ float red[4][2][HD];
    const int wave = threadIdx.x >> 6, lane = threadIdx.x & 63;
    const float vb1 = b1[lane], vb2 = b2[lane];
    float s1 = 0.f, s2 = 0.f;
    for (int node = blockIdx.x * 4 + wave; node < NN; node += MLP_BLOCKS * 4) {
        const int idx = node * HD + lane;
        z0s[wave][lane] = ADD_H ? (h[idx] + zin_t2[idx]) : zin_t2[idx];
        float a = vb1;
#pragma unroll
        for (int k = 0; k < HD; ++k)
            a = fmaf(z0s[wave][k], w1[k * HD + lane], a);
        a = fmaxf(a, 0.f);
        t1s[wave][lane] = a;
        float o = vb2;
#pragma unroll
        for (int k = 0; k < HD; ++k)
            o = fmaf(t1s[wave][k], w2[k * HD + lane], o);
        zin_t2[idx] = o;
        s1 += o;
        s2 += o * o;
    }
    red[wave][0][lane] = s1;
    red[wave][1][lane] = s2;
    __syncthreads();
    if (wave == 0) {
        float a = red[0][0][lane] + red[1][0][lane] + red[2][0][lane] + red[3][0][lane];
        float c = red[0][1][lane] + red[1][1][lane] + red[2][1][lane] + red[3][1][lane];
        part[blockIdx.x * 128 + lane] = a;
        part[blockIdx.x * 128 + 64 + lane] = c;
    }
}

// ================= BN stats finalize (1 block x 1024) =================
__global__ __launch_bounds__(1024) void k_bn_final(
    const float* __restrict__ part,
    const float* __restrict__ g, const float* __restrict__ b,
    float* __restrict__ bnp)
{
    __shared__ float red[16][2][HD];
    const int c = threadIdx.x & 63;
    const int s = threadIdx.x >> 6;
    float s1 = 0.f, s2 = 0.f;
    for (int i = s; i < MLP_BLOCKS; i += 16) {
        s1 += part[i * 128 + c];
        s2 += part[i * 128 + 64 + c];
    }
    red[s][0][c] = s1;
    red[s][1][c] = s2;
    __syncthreads();
    if (s == 0) {
        float a = 0.f, q = 0.f;
#pragma unroll
        for (int i = 0; i < 16; ++i) { a += red[i][0][c]; q += red[i][1][c]; }
        const float mu  = a / (float)NN;
        const float var = q / (float)NN - mu * mu;
        const float rstd = rsqrtf(var + BN_EPS);
        const float sc = rstd * g[c];
        bnp[c] = sc;
        bnp[64 + c] = b[c] - mu * sc;
    }
}

// ========= BN apply + ReLU; writes f32 h (d_out) and bf16 mirror =========
__global__ __launch_bounds__(256) void k_bn_apply(
    const float* __restrict__ t2, const float* __restrict__ bnp,
    float* __restrict__ h, ushort16* __restrict__ hb)
{
    const int lane = threadIdx.x & 63;
    const float sc = bnp[lane];
    const float sh = bnp[64 + lane];
    int i = blockIdx.x * 256 + threadIdx.x;
    const int stride = APPLY_BLOCKS * 256;
    for (; i < NN * HD; i += stride) {
        const float v = fmaxf(t2[i] * sc + sh, 0.f);
        h[i] = v;
        if (hb) hb[i] = f2b(v);
    }
}

// ================= global mean pool (batch sorted; 4 waves/graph) ==========
__global__ __launch_bounds__(256) void k_pool(
    const float* __restrict__ h, const int* __restrict__ batch,
    float* __restrict__ emb)
{
    __shared__ float red[4][HD];
    const int g = blockIdx.x;
    const int lane = threadIdx.x & 63;
    const int wave = threadIdx.x >> 6;
    int lo = 0, hi = NN;
    while (lo < hi) { int m = (lo + hi) >> 1; if (batch[m] < g) lo = m + 1; else hi = m; }
    const int start = lo;
    hi = NN;
    while (lo < hi) { int m = (lo + hi) >> 1; if (batch[m] <= g) lo = m + 1; else hi = m; }
    const int end = lo;
    float acc = 0.f;
    for (int n = start + wave; n < end; n += 4) acc += h[(size_t)n * HD + lane];
    red[wave][lane] = acc;
    __syncthreads();
    if (wave == 0) {
        float a = red[0][lane] + red[1][lane] + red[2][lane] + red[3][lane];
        emb[g * HD + lane] = a / fmaxf((float)(end - start), 1.f);
    }
}

extern "C" void kernel_launch(void* const* d_in, const int* in_sizes, int n_in,
                              void* d_out, int out_size, void* d_ws, size_t ws_size,
                              hipStream_t stream)
{
    const float* x     = (const float*)d_in[0];
    const float* ea    = (const float*)d_in[1];
    const int*   ei    = (const int*)d_in[2];
    const int*   batch = (const int*)d_in[3];
    const float* np_w  = (const float*)d_in[4];
    const float* np_b  = (const float*)d_in[5];
    const float* ep_w  = (const float*)d_in[6];
    const float* ep_b  = (const float*)d_in[7];
    const float* w1    = (const float*)d_in[8];
    const float* b1    = (const float*)d_in[9];
    const float* w2    = (const float*)d_in[10];
    const float* b2    = (const float*)d_in[11];
    const float* bng   = (const float*)d_in[12];
    const float* bnb   = (const float*)d_in[13];

    // h lives directly in d_out (f32): [NN*HD] then graph_emb [NG*HD]
    float* h   = (float*)d_out;
    float* emb = h + (size_t)NN * HD;

    char* ws = (char*)d_ws;
    float*     agg     = (float*)    (ws);               // 25,600,000 (z / t2)
    float*     part    = (float*)    (ws + 25600000);    //  1,048,576
    float*     bnp     = (float*)    (ws + 26648576);    //        512
    int*       deg     = (int*)      (ws + 26649088);    //    400,000
    int*       rowptr  = (int*)      (ws + 27049088);    //    400,016
    int*       cur     = (int*)      (ws + 27449104);    //    400,000
    ushort16*  hb      = (ushort16*) (ws + 27849104);    // 12,800,000 (bf16 h)
    int2*      perm_se = (int2*)     (ws + 40649104);    // 25,600,000
    ushort16*  ea_perm = (ushort16*) (ws + 66249104);    // 102,400,000 (bf16)

    const size_t NEED_A = 66249104u + 102400000u;   // ~168.6 MB
    const size_t NEED_B = 66249104u;                // ~66.2 MB
    const int mode = (ws_size >= NEED_A) ? 0 : (ws_size >= NEED_B) ? 1 : 2;

    k_node_proj<<<NN / 4, 256, 0, stream>>>(x, np_w, np_b, h,
                                            (mode != 2) ? hb : (ushort16*)nullptr);

    if (mode != 2) {
        hipMemsetAsync(deg, 0, NN * sizeof(int), stream);
        k_hist<<<NE / 256, 256, 0, stream>>>(ei, deg);
        k_scan<<<1, SCAN_T, 0, stream>>>(deg, rowptr, cur);
        k_scatter<<<NE / 256, 256, 0, stream>>>(ei, cur, perm_se);
        if (mode == 0)
            k_permute<<<NE * 4 / 256, 256, 0, stream>>>(ea, perm_se, ea_perm);
    }

    for (int l = 0; l < NL; ++l) {
        if (mode == 0) {
            k_gather<0><<<NN / 4, 256, 0, stream>>>(ea_perm, ea, perm_se, rowptr,
                                                    ep_w, ep_b, hb, h, agg);
            k_mlp<false><<<MLP_BLOCKS, 256, 0, stream>>>(h, agg, w1 + l * HD * HD, b1 + l * HD,
                                                         w2 + l * HD * HD, b2 + l * HD, part);
        } else if (mode == 1) {
            k_gather<1><<<NN / 4, 256, 0, stream>>>(ea_perm, ea, perm_se, rowptr,
                                                    ep_w, ep_b, hb, h, agg);
            k_mlp<false><<<MLP_BLOCKS, 256, 0, stream>>>(h, agg, w1 + l * HD * HD, b1 + l * HD,
                                                         w2 + l * HD * HD, b2 + l * HD, part);
        } else {
            hipMemsetAsync(agg, 0, (size_t)NN * HD * sizeof(float), stream);
            k_edge_msg<<<EDGE_BLOCKS, 256, 0, stream>>>(ea, ei, ep_w, ep_b, h, agg);
            k_mlp<true><<<MLP_BLOCKS, 256, 0, stream>>>(h, agg, w1 + l * HD * HD, b1 + l * HD,
                                                        w2 + l * HD * HD, b2 + l * HD, part);
        }
        k_bn_final<<<1, 1024, 0, stream>>>(part, bng + l * HD, bnb + l * HD, bnp);
        k_bn_apply<<<APPLY_BLOCKS, 256, 0, stream>>>(
            agg, bnp, h,
            (mode != 2 && l != NL - 1) ? hb : (ushort16*)nullptr);
    }

    k_pool<<<NG, 256, 0, stream>>>(h, batch, emb);
}

// Round 7
// 1253.701 us; speedup vs baseline: 1.9264x; 1.3948x over previous
//
#include <hip/hip_runtime.h>
#include <hip/hip_bf16.h>

#define NN 100000
#define NE 3200000
#define IND 128
#define ED 16
#define HD 64
#define NL 3
#define NG 256
#define BN_EPS 1e-5f

#define NB 391          // buckets of 256 nodes: ceil(NN/256)
#define PBLK 512        // partition blocks
#define PCHUNK 6250     // NE / PBLK exactly
#define MLP_BLOCKS 2048
#define APPLY_BLOCKS 2048

typedef unsigned int uint32;
typedef unsigned long long uint64;
typedef unsigned short ushort16;

// f32 -> bf16 bits, round-to-nearest-even
__device__ __forceinline__ ushort16 f2b(float f) {
    uint32 u = __float_as_uint(f);
    u = (u + 0x7fffu + ((u >> 16) & 1u)) >> 16;
    return (ushort16)u;
}
__device__ __forceinline__ float b2f(ushort16 b) {
    return __uint_as_float(((uint32)b) << 16);
}

// ========== node projection: sb = bf16(x @ np_w + np_b) ==========
__global__ __launch_bounds__(256) void k_node_proj(
    const float* __restrict__ x, const float* __restrict__ w,
    const float* __restrict__ b, ushort16* __restrict__ sb)
{
    __shared__ float xs[4][IND];
    const int wave = threadIdx.x >> 6, lane = threadIdx.x & 63;
    const int node = blockIdx.x * 4 + wave;   // grid = NN/4 exactly
    const float2 v = *(const float2*)(x + (size_t)node * IND + lane * 2);
    ((float2*)xs[wave])[lane] = v;
    // same-wave LDS write->read: hardware-ordered per wave
    float acc = b[lane];
#pragma unroll
    for (int k = 0; k < IND; ++k)
        acc = fmaf(xs[wave][k], w[k * HD + lane], acc);
    sb[node * HD + lane] = f2b(acc);
}

// ========== P1: per-block bucket histogram ==========
__global__ __launch_bounds__(256) void k_p1(const int* __restrict__ ei,
                                            int* __restrict__ bh)
{
    __shared__ int hist[NB];
    const int t = threadIdx.x, blk = blockIdx.x;
    for (int i = t; i < NB; i += 256) hist[i] = 0;
    __syncthreads();
    const int base = blk * PCHUNK;
    for (int i = t; i < PCHUNK; i += 256)
        atomicAdd(&hist[ei[NE + base + i] >> 8], 1);
    __syncthreads();
    for (int i = t; i < NB; i += 256) bh[blk * NB + i] = hist[i];
}

// ========== P2: scan bh over blocks per bucket + bucket bases ==========
__global__ __launch_bounds__(512) void k_p2(int* __restrict__ bh,
                                            int* __restrict__ bstart,
                                            int* __restrict__ rowptr)
{
    __shared__ int tot[NB];
    __shared__ int bsl[NB + 1];
    const int t = threadIdx.x;
    if (t < NB) {
        int s = 0;
        for (int blk = 0; blk < PBLK; ++blk) {
            const int idx = blk * NB + t;
            const int v = bh[idx];
            bh[idx] = s;          // within-bucket prefix over blocks
            s += v;
        }
        tot[t] = s;
    }
    __syncthreads();
    if (t == 0) {
        int run = 0;
        for (int b = 0; b < NB; ++b) { bsl[b] = run; run += tot[b]; }
        bsl[NB] = run;            // == NE
    }
    __syncthreads();
    if (t < NB) {
        const int base = bsl[t];
        for (int blk = 0; blk < PBLK; ++blk) bh[blk * NB + t] += base;
        bstart[t] = base;
    }
    if (t == 0) { bstart[NB] = NE; rowptr[NN] = NE; }
}

// ========== P3: partition edges into buckets (L2-merged writes) ==========
// pack: dst(17) | src(17)<<17 | eid(22)<<34
__global__ __launch_bounds__(256) void k_p3(const int* __restrict__ ei,
                                            const int* __restrict__ bh,
                                            uint64* __restrict__ tmp)
{
    __shared__ int cursor[NB];
    const int t = threadIdx.x, blk = blockIdx.x;
    for (int i = t; i < NB; i += 256) cursor[i] = bh[blk * NB + i];
    __syncthreads();
    const int base = blk * PCHUNK;
    for (int i = t; i < PCHUNK; i += 256) {
        const int e = base + i;
        const int d = ei[NE + e];
        const int s = ei[e];
        const int pos = atomicAdd(&cursor[d >> 8], 1);
        tmp[pos] = (uint64)(uint32)d | ((uint64)(uint32)s << 17)
                 | ((uint64)(uint32)e << 34);
    }
}

// ========== P4: exact counting-sort within bucket; emits perm_se+rowptr ====
__global__ __launch_bounds__(256) void k_p4(const uint64* __restrict__ tmp,
                                            const int* __restrict__ bstart,
                                            int2* __restrict__ perm_se,
                                            int* __restrict__ rowptr)
{
    __shared__ int cnt[256], csave[256], cnt2[256];
    const int t = threadIdx.x, b = blockIdx.x;
    const int lo = bstart[b], hi = bstart[b + 1];
    cnt[t] = 0; cnt2[t] = 0;
    __syncthreads();
    for (int e = lo + t; e < hi; e += 256)
        atomicAdd(&cnt[(int)(tmp[e] & 0x1FFFF) & 255], 1);
    __syncthreads();
    csave[t] = cnt[t];
    __syncthreads();
    // inclusive scan of cnt
    for (int off = 1; off < 256; off <<= 1) {
        const int v = (t >= off) ? cnt[t - off] : 0;
        __syncthreads();
        cnt[t] += v;
        __syncthreads();
    }
    const int excl = cnt[t] - csave[t];
    const int node = (b << 8) + t;
    if (node < NN) rowptr[node] = lo + excl;
    __syncthreads();
    csave[t] = excl;
    __syncthreads();
    for (int e = lo + t; e < hi; e += 256) {
        const uint64 u = tmp[e];
        const int loc = (int)(u & 0x1FFFF) & 255;
        const int r = atomicAdd(&cnt2[loc], 1);
        const int pos = lo + csave[loc] + r;
        perm_se[pos] = make_int2((int)((u >> 17) & 0x1FFFF), (int)(u >> 34));
    }
}

// ========== permute edge_attr rows to dst-order, f32 -> bf16 ==========
__global__ __launch_bounds__(256) void k_permute(
    const float* __restrict__ ea, const int2* __restrict__ perm_se,
    ushort16* __restrict__ ea_perm)
{
    const int pos = blockIdx.x * 256 + threadIdx.x;  // grid = NE*4/256
    const int p = pos >> 2, q = pos & 3;
    const int eid = perm_se[p].y;
    const float4 v = ((const float4*)(ea + (size_t)eid * ED))[q];
    ushort4 o;
    o.x = f2b(v.x); o.y = f2b(v.y); o.z = f2b(v.z); o.w = f2b(v.w);
    ((ushort4*)ea_perm)[pos] = o;
}

// ========== gather + on-the-fly BN/ReLU of the PREVIOUS layer ==========
// wave per node (lane = column). XFORM=false: layer 0 (state = proj).
// XFORM=true: state = prev t2 (bf16); h = relu(t2*sc + sh) applied inline.
template <bool XFORM>
__global__ __launch_bounds__(256) void k_gather(
    const ushort16* __restrict__ eab, const int2* __restrict__ perm_se,
    const int* __restrict__ rowptr,
    const float* __restrict__ epw, const float* __restrict__ epb,
    const ushort16* __restrict__ sb, const float* __restrict__ bnp,
    float* __restrict__ z)
{
    const int lane = threadIdx.x & 63;
    float wr[ED];
#pragma unroll
    for (int k = 0; k < ED; ++k) wr[k] = epw[k * HD + lane];
    const float bc = epb[lane];
    const float tsc = XFORM ? bnp[lane] : 1.f;
    const float tsh = XFORM ? bnp[64 + lane] : 0.f;

    const int node = __builtin_amdgcn_readfirstlane((blockIdx.x << 2) + (threadIdx.x >> 6));
    const int rs = rowptr[node];
    const int re = rowptr[node + 1];

    float acc = 0.f;
    int j = rs;
    for (; j + 8 <= re; j += 8) {
        int s[8];
#pragma unroll
        for (int m = 0; m < 8; ++m) s[m] = perm_se[j + m].x;
        float hv[8];
#pragma unroll
        for (int m = 0; m < 8; ++m) {
            float v = b2f(sb[(size_t)s[m] * HD + lane]);
            if (XFORM) v = fmaxf(fmaf(v, tsc, tsh), 0.f);
            hv[m] = v;
        }
#pragma unroll
        for (int m = 0; m < 8; ++m) {
            const uint32* r = (const uint32*)(eab + (size_t)(j + m) * ED);
            float e = bc;
#pragma unroll
            for (int k2 = 0; k2 < ED / 2; ++k2) {
                const uint32 u = r[k2];
                e = fmaf(__uint_as_float(u << 16), wr[2 * k2], e);
                e = fmaf(__uint_as_float(u & 0xffff0000u), wr[2 * k2 + 1], e);
            }
            acc += fmaxf(hv[m] + e, 0.f);
        }
    }
    for (; j < re; ++j) {
        float v = b2f(sb[(size_t)perm_se[j].x * HD + lane]);
        if (XFORM) v = fmaxf(fmaf(v, tsc, tsh), 0.f);
        const uint32* r = (const uint32*)(eab + (size_t)j * ED);
        float e = bc;
#pragma unroll
        for (int k2 = 0; k2 < ED / 2; ++k2) {
            const uint32 u = r[k2];
            e = fmaf(__uint_as_float(u << 16), wr[2 * k2], e);
            e = fmaf(__uint_as_float(u & 0xffff0000u), wr[2 * k2 + 1], e);
        }
        acc += fmaxf(v + e, 0.f);
    }
    // self term, same transform
    float u0 = b2f(sb[(size_t)node * HD + lane]);
    if (XFORM) u0 = fmaxf(fmaf(u0, tsc, tsh), 0.f);
    z[node * HD + lane] = acc + u0;
}

// ========== MLP + BN partial stats ==========
// STORE_BF16: layers 0,1 write bf16 state (pre-BN t2); layer 2 writes f32
// in place over z (each element read by the same thread before overwrite).
template <bool STORE_BF16>
__global__ __launch_bounds__(256) void k_mlp(
    float* __restrict__ z,
    const float* __restrict__ w1, const float* __restrict__ b1,
    const float* __restrict__ w2, const float* __restrict__ b2,
    ushort16* __restrict__ sb, float* __restrict__ part)
{
    __shared__ float z0s[4][HD];
    __shared__ float t1s[4][HD];
    __shared__ float red[4][2][HD];
    const int wave = threadIdx.x >> 6, lane = threadIdx.x & 63;
    const float vb1 = b1[lane], vb2 = b2[lane];
    float s1 = 0.f, s2 = 0.f;
    for (int node = blockIdx.x * 4 + wave; node < NN; node += MLP_BLOCKS * 4) {
        const int idx = node * HD + lane;
        z0s[wave][lane] = z[idx];
        float a = vb1;
#pragma unroll
        for (int k = 0; k < HD; ++k)
            a = fmaf(z0s[wave][k], w1[k * HD + lane], a);
        a = fmaxf(a, 0.f);
        t1s[wave][lane] = a;
        float o = vb2;
#pragma unroll
        for (int k = 0; k < HD; ++k)
            o = fmaf(t1s[wave][k], w2[k * HD + lane], o);
        if (STORE_BF16) sb[idx] = f2b(o);
        else            z[idx] = o;
        s1 += o;
        s2 += o * o;
    }
    red[wave][0][lane] = s1;
    red[wave][1][lane] = s2;
    __syncthreads();
    if (wave == 0) {
        float a = red[0][0][lane] + red[1][0][lane] + red[2][0][lane] + red[3][0][lane];
        float c = red[0][1][lane] + red[1][1][lane] + red[2][1][lane] + red[3][1][lane];
        part[blockIdx.x * 128 + lane] = a;
        part[blockIdx.x * 128 + 64 + lane] = c;
    }
}

// ========== BN stats finalize (1 block x 1024) ==========
__global__ __launch_bounds__(1024) void k_bn_final(
    const float* __restrict__ part,
    const float* __restrict__ g, const float* __restrict__ b,
    float* __restrict__ bnp)
{
    __shared__ float red[16][2][HD];
    const int c = threadIdx.x & 63;
    const int s = threadIdx.x >> 6;
    float s1 = 0.f, s2 = 0.f;
    for (int i = s; i < MLP_BLOCKS; i += 16) {
        s1 += part[i * 128 + c];
        s2 += part[i * 128 + 64 + c];
    }
    red[s][0][c] = s1;
    red[s][1][c] = s2;
    __syncthreads();
    if (s == 0) {
        float a = 0.f, q = 0.f;
#pragma unroll
        for (int i = 0; i < 16; ++i) { a += red[i][0][c]; q += red[i][1][c]; }
        const float mu  = a / (float)NN;
        const float var = q / (float)NN - mu * mu;
        const float rstd = rsqrtf(var + BN_EPS);
        const float sc = rstd * g[c];
        bnp[c] = sc;
        bnp[64 + c] = b[c] - mu * sc;
    }
}

// ========== final BN apply + ReLU -> h (d_out, f32) ==========
__global__ __launch_bounds__(256) void k_bn_apply(
    const float* __restrict__ t2, const float* __restrict__ bnp,
    float* __restrict__ h)
{
    const int lane = threadIdx.x & 63;
    const float sc = bnp[lane];
    const float sh = bnp[64 + lane];
    int i = blockIdx.x * 256 + threadIdx.x;
    const int stride = APPLY_BLOCKS * 256;
    for (; i < NN * HD; i += stride)
        h[i] = fmaxf(t2[i] * sc + sh, 0.f);
}

// ========== global mean pool (batch sorted; 4 waves/graph) ==========
__global__ __launch_bounds__(256) void k_pool(
    const float* __restrict__ h, const int* __restrict__ batch,
    float* __restrict__ emb)
{
    __shared__ float red[4][HD];
    const int g = blockIdx.x;
    const int lane = threadIdx.x & 63;
    const int wave = threadIdx.x >> 6;
    int lo = 0, hi = NN;
    while (lo < hi) { int m = (lo + hi) >> 1; if (batch[m] < g) lo = m + 1; else hi = m; }
    const int start = lo;
    hi = NN;
    while (lo < hi) { int m = (lo + hi) >> 1; if (batch[m] <= g) lo = m + 1; else hi = m; }
    const int end = lo;
    float acc = 0.f;
    for (int n = start + wave; n < end; n += 4) acc += h[(size_t)n * HD + lane];
    red[wave][lane] = acc;
    __syncthreads();
    if (wave == 0) {
        float a = red[0][lane] + red[1][lane] + red[2][lane] + red[3][lane];
        emb[g * HD + lane] = a / fmaxf((float)(end - start), 1.f);
    }
}

extern "C" void kernel_launch(void* const* d_in, const int* in_sizes, int n_in,
                              void* d_out, int out_size, void* d_ws, size_t ws_size,
                              hipStream_t stream)
{
    const float* x     = (const float*)d_in[0];
    const float* ea    = (const float*)d_in[1];
    const int*   ei    = (const int*)d_in[2];
    const int*   batch = (const int*)d_in[3];
    const float* np_w  = (const float*)d_in[4];
    const float* np_b  = (const float*)d_in[5];
    const float* ep_w  = (const float*)d_in[6];
    const float* ep_b  = (const float*)d_in[7];
    const float* w1    = (const float*)d_in[8];
    const float* b1    = (const float*)d_in[9];
    const float* w2    = (const float*)d_in[10];
    const float* b2    = (const float*)d_in[11];
    const float* bng   = (const float*)d_in[12];
    const float* bnb   = (const float*)d_in[13];

    // final h lives directly in d_out (f32): [NN*HD] then graph_emb [NG*HD]
    float* h   = (float*)d_out;
    float* emb = h + (size_t)NN * HD;

    char* ws = (char*)d_ws;
    float*     agg     = (float*)    (ws);               // 25,600,000 (z / t2f; aliases tmp)
    uint64*    tmp     = (uint64*)   (ws);               // 25,600,000 (P3/P4 only)
    float*     part    = (float*)    (ws + 25600000);    //  1,048,576
    float*     bnp     = (float*)    (ws + 26648576);    //  1,536 (3 layers x 128)
    int*       bh      = (int*)      (ws + 26650112);    //  800,768 (PBLK x NB)
    int*       bstart  = (int*)      (ws + 27450880);    //  1,568
    int*       rowptr  = (int*)      (ws + 27452448);    //  400,016
    ushort16*  sb      = (ushort16*) (ws + 27852464);    // 12,800,000 (bf16 state)
    int2*      perm_se = (int2*)     (ws + 40652464);    // 25,600,000
    ushort16*  ea_perm = (ushort16*) (ws + 66252464);    // 102,400,000
    // total ~168.7 MB (ws_size >= 245 MB demonstrated in rounds 2-4)

    k_node_proj<<<NN / 4, 256, 0, stream>>>(x, np_w, np_b, sb);

    // CSR build: partition sort (all random writes L2-block-local)
    k_p1<<<PBLK, 256, 0, stream>>>(ei, bh);
    k_p2<<<1, 512, 0, stream>>>(bh, bstart, rowptr);
    k_p3<<<PBLK, 256, 0, stream>>>(ei, bh, tmp);
    k_p4<<<NB, 256, 0, stream>>>(tmp, bstart, perm_se, rowptr);
    k_permute<<<NE * 4 / 256, 256, 0, stream>>>(ea, perm_se, ea_perm);

    for (int l = 0; l < NL; ++l) {
        if (l == 0)
            k_gather<false><<<NN / 4, 256, 0, stream>>>(
                ea_perm, perm_se, rowptr, ep_w, ep_b, sb, bnp, agg);
        else
            k_gather<true><<<NN / 4, 256, 0, stream>>>(
                ea_perm, perm_se, rowptr, ep_w, ep_b, sb, bnp + (l - 1) * 128, agg);
        if (l < NL - 1)
            k_mlp<true><<<MLP_BLOCKS, 256, 0, stream>>>(
                agg, w1 + l * HD * HD, b1 + l * HD, w2 + l * HD * HD, b2 + l * HD,
                sb, part);
        else
            k_mlp<false><<<MLP_BLOCKS, 256, 0, stream>>>(
                agg, w1 + l * HD * HD, b1 + l * HD, w2 + l * HD * HD, b2 + l * HD,
                sb, part);
        k_bn_final<<<1, 1024, 0, stream>>>(part, bng + l * HD, bnb + l * HD, bnp + l * 128);
    }

    k_bn_apply<<<APPLY_BLOCKS, 256, 0, stream>>>(agg, bnp + 2 * 128, h);
    k_pool<<<NG, 256, 0, stream>>>(h, batch, emb);
}